// Round 11
// baseline (368.043 us; speedup 1.0000x reference)
//
#include <hip/hip_runtime.h>

// Acoustic stress-velocity FD propagator, MI355X — persistent kernel v11.
// Reverted to v6's PROVEN all-far (sc0 sc1, MALL-coherent) protocol after
// three near-scope hangs (v8/v9/v10) — near-scope abandoned as undebuggable.
// v6 + three safe sync-chain trims:
//  1) central-tile publish issued inside tau=7's pressure phase (store
//     latency hides under sp-write + barrier);
//  2) ring threads self-poll their own source's flag and self-reload
//     (drops the proxy barrier; per-direction decoupling). All far scope,
//     dense flags — single-scope, so no line-sharing hazard;
//  3) tau=7 receiver record moved after the flag store (overlaps polls).
// Parity double-buffer + flag transitivity close the WAR race exactly as
// v5/v6: my pb(l) read < my flag(l+2) < neighbor's epoch-(l+2) publish.

#define NXc 256
#define NZc 256
#define NTc 400
#define NSc 4
#define NRc 128

#define TS 8                    // steps per epoch = halo depth
#define Bt 32                   // tile edge
#define NSTR 12                 // 4-wide strips per region row
#define BT 576                  // threads = 48 rows x 12 strips
#define LROW 48                 // region edge / LDS row stride
#define LSZ ((48 + 2) * LROW)   // 2400: one pad row above/below
#define NBLK (NSc * 64)         // 256 blocks
#define NEP (NTc / TS)          // 50 epochs

constexpr float DT_H    = 0.001f;
constexpr float INV_D   = 0.1f;            // 1/DX = 1/DZ
constexpr float SRC_AMP = 0.001f * 0.01f;  // DT/(DX*DZ)
constexpr int   NXZ     = NXc * NZc;

typedef float f32x4 __attribute__((ext_vector_type(4)));

__device__ __forceinline__ unsigned ldu_far(const unsigned* p) {
    unsigned v;
    asm volatile("global_load_dword %0, %1, off sc0 sc1\n\t"
                 "s_waitcnt vmcnt(0)" : "=&v"(v) : "v"(p) : "memory");
    return v;
}
__device__ __forceinline__ void stu_far(unsigned* p, unsigned v) {
    asm volatile("global_store_dword %0, %1, off sc0 sc1"
                 :: "v"(p), "v"(v) : "memory");
}

__global__ __launch_bounds__(BT) void prop_kernel(
    float* __restrict__ xchg, unsigned* __restrict__ flags,
    const float* __restrict__ vp, const float* __restrict__ rho,
    const float* __restrict__ damp, const float* __restrict__ wavelet,
    const int* __restrict__ src_x, const int* __restrict__ src_z,
    const int* __restrict__ rcv_x, const int* __restrict__ rcv_z,
    float* __restrict__ out)
{
    __shared__ float sp[LSZ], svx[LSZ];
    __shared__ float spE[BT + 1], svzE[BT + 1];

    const int tid  = threadIdx.x;
    const int bid  = blockIdx.x;
    const int s    = bid >> 6;
    const int tile = bid & 63;
    const int tx = tile >> 3, tz = tile & 7;
    const int gx0 = tx * Bt - TS, gz0 = tz * Bt - TS;

    const int li  = tid / NSTR;            // region row 0..47
    const int st  = tid - li * NSTR;       // strip 0..11
    const int lk0 = st * 4;
    const int gi  = gx0 + li;
    const int gk0 = gz0 + lk0;             // 4-aligned; strip fully in or out
    const bool in = ((unsigned)gi < (unsigned)NXc) &&
                    ((unsigned)gk0 < (unsigned)NZc);
    const int c4 = s * NXZ + gi * NZc + gk0;
    const bool central = in && ((unsigned)(li - TS) < (unsigned)Bt)
                            && (lk0 >= TS) && (lk0 <= TS + Bt - 4);
    const bool ring = in && !central;

    const size_t F = (size_t)NSc * NXZ;
    float* b0 = xchg;            // epoch parity 0: {p, vx, vz}
    float* b1 = xchg + 3 * F;    // epoch parity 1

    // ---- time-invariant per-cell coefficients (registers, once) ----
    float pr[4]  = {0, 0, 0, 0};
    float vxr[4] = {0, 0, 0, 0};
    float vzr[4] = {0, 0, 0, 0};
    float fr[4], bxr[4], bzr[4], dkxr[4], dkzr[4], sfr[4];
    {
        const int sx = src_x[s], sz = src_z[s];
        if (in) {
            float4 r4 = *(const float4*)(rho  + c4 - s * NXZ);
            float4 v4 = *(const float4*)(vp   + c4 - s * NXZ);
            float4 d4 = *(const float4*)(damp + c4 - s * NXZ);
            float rv[4] = {r4.x, r4.y, r4.z, r4.w};
            float vv[4] = {v4.x, v4.y, v4.z, v4.w};
            float dv[4] = {d4.x, d4.y, d4.z, d4.w};
#pragma unroll
            for (int k = 0; k < 4; ++k) {
                int gk = gk0 + k;
                fr[k] = 1.0f - DT_H * dv[k];
                float bi = DT_H / rv[k] * INV_D;
                bxr[k] = (gi == NXc - 1) ? 0.f : bi;   // _dxf zero-pad
                bzr[k] = (gk == NZc - 1) ? 0.f : bi;   // _dzf zero-pad
                float dk = DT_H * rv[k] * vv[k] * vv[k] * INV_D;
                dkxr[k] = (gi == 0) ? 0.f : dk;        // _dxb zero-pad
                dkzr[k] = (gk == 0) ? 0.f : dk;        // _dzb zero-pad
                sfr[k]  = (gi == sx && gk == sz) ? SRC_AMP : 0.f;
            }
        } else {
#pragma unroll
            for (int k = 0; k < 4; ++k) {
                fr[k] = 0.f; bxr[k] = 0.f; bzr[k] = 0.f;
                dkxr[k] = 0.f; dkzr[k] = 0.f; sfr[k] = 0.f;
            }
        }
    }

    // Pads (never overwritten: steps write rows 1..48 only).
    if (tid < LROW) {
        sp[tid] = 0.f; svx[tid] = 0.f;
        sp[LSZ - LROW + tid] = 0.f; svx[LSZ - LROW + tid] = 0.f;
    }
    if (tid == 0) { svzE[0] = 0.f; spE[BT] = 0.f; }

    // Receivers (loaded once).
    int rxv = 0, rzv = 0;
    if (tid < NRc) { rxv = rcv_x[tid]; rzv = rcv_z[tid]; }
    const bool rown = (tid < NRc) &&
        ((unsigned)(rxv - tx * Bt) < (unsigned)Bt) &&
        ((unsigned)(rzv - tz * Bt) < (unsigned)Bt);
    const int rj = (rxv - gx0 + 1) * LROW + (rzv - gz0);
    float* obase = out + (size_t)s * NTc * NRc + tid;
    const float* wb = wavelet + s * NTc;

    // My source neighbor (ring threads only): the tile whose central area
    // contains my strip. Always exists for in-domain ring strips.
    const int sdx = (li  < TS) ? -1 : (li  < TS + Bt) ? 0 : 1;
    const int sdz = (lk0 < TS) ? -1 : (lk0 < TS + Bt) ? 0 : 1;
    const int snb = (s << 6) + (tx + sdx) * 8 + (tz + sdz);

    const int jb = (li + 1) * LROW + lk0;

    for (int l = 0; l < NEP; ++l) {
        const bool notLast = (l < NEP - 1);
        float* pb = (l & 1) ? b1 : b0;

        // Refresh sp/spE (ring regs were just reloaded; central unchanged).
        *(float4*)&sp[jb] = make_float4(pr[0], pr[1], pr[2], pr[3]);
        spE[tid] = pr[0];
        __syncthreads();

        for (int tau = 0; tau < TS; ++tau) {
            // ---- velocity: reads sp/spE, writes svx + vz edge line ----
            float4 pn4 = *(const float4*)&sp[jb + LROW];  // row+1 strip
            float  pze = spE[tid + 1];                    // next strip p[0]
            float pnx[4] = {pn4.x, pn4.y, pn4.z, pn4.w};
            float pz1[4] = {pr[1], pr[2], pr[3], pze};
#pragma unroll
            for (int k = 0; k < 4; ++k) {
                vxr[k] = fr[k] * vxr[k] - bxr[k] * (pnx[k] - pr[k]);
                vzr[k] = fr[k] * vzr[k] - bzr[k] * (pz1[k] - pr[k]);
            }
            *(float4*)&svx[jb] = make_float4(vxr[0], vxr[1], vxr[2], vxr[3]);
            svzE[tid + 1] = vzr[3];
            __syncthreads();

            // ---- pressure: reads svx + edge line, writes sp/spE ----
            const float wv = wb[l * TS + tau];
            float4 vxm4 = *(const float4*)&svx[jb - LROW]; // row-1 (new vx)
            float  vzm0 = svzE[tid];                       // prev strip vz[3]
            float vxm[4] = {vxm4.x, vxm4.y, vxm4.z, vxm4.w};
            float vzm[4] = {vzm0, vzr[0], vzr[1], vzr[2]};
#pragma unroll
            for (int k = 0; k < 4; ++k) {
                pr[k] = fr[k] * pr[k]
                      - dkxr[k] * (vxr[k] - vxm[k])
                      - dkzr[k] * (vzr[k] - vzm[k])
                      + sfr[k] * wv;
            }
            // Publish overlapped: issue MALL stores as soon as the final
            // pr is known; latency hides under sp-write + barrier.
            if (tau == TS - 1 && notLast && central) {
                f32x4 a = {pr[0], pr[1], pr[2], pr[3]};
                f32x4 b = {vxr[0], vxr[1], vxr[2], vxr[3]};
                f32x4 c = {vzr[0], vzr[1], vzr[2], vzr[3]};
                asm volatile(
                    "global_store_dwordx4 %0, %3, off sc0 sc1\n\t"
                    "global_store_dwordx4 %1, %4, off sc0 sc1\n\t"
                    "global_store_dwordx4 %2, %5, off sc0 sc1"
                    :: "v"(pb + c4), "v"(pb + F + c4), "v"(pb + 2 * F + c4),
                       "v"(a), "v"(b), "v"(c)
                    : "memory");
            }
            *(float4*)&sp[jb] = make_float4(pr[0], pr[1], pr[2], pr[3]);
            spE[tid] = pr[0];
            __syncthreads();

            // Receiver record taus 0..6 (tau 7 handled below, overlapped
            // with the neighbor polls). sp stable through next velocity.
            if (tau < TS - 1 && rown)
                obase[(size_t)(l * TS + tau) * NRc] = sp[rj];
        }

        if (notLast) {
            // Release: drain all stores (publish + receiver), then flag.
            asm volatile("s_waitcnt vmcnt(0)" ::: "memory");
            __syncthreads();
            if (tid == 0) stu_far(flags + bid, (unsigned)(l + 1));
            // tau-7 receiver record overlaps the polls below.
            if (rown) obase[(size_t)(l * TS + TS - 1) * NRc] = sp[rj];
            // Ring threads self-poll their source, then self-reload.
            if (ring) {
                const unsigned want = (unsigned)(l + 1);
                const unsigned* fp = flags + snb;
                while (ldu_far(fp) < want) __builtin_amdgcn_s_sleep(1);
                f32x4 a, b, c;
                asm volatile(
                    "global_load_dwordx4 %0, %3, off sc0 sc1\n\t"
                    "global_load_dwordx4 %1, %4, off sc0 sc1\n\t"
                    "global_load_dwordx4 %2, %5, off sc0 sc1\n\t"
                    "s_waitcnt vmcnt(0)"
                    : "=&v"(a), "=&v"(b), "=&v"(c)
                    : "v"(pb + c4), "v"(pb + F + c4), "v"(pb + 2 * F + c4)
                    : "memory");
                pr[0]=a.x; pr[1]=a.y; pr[2]=a.z; pr[3]=a.w;
                vxr[0]=b.x; vxr[1]=b.y; vxr[2]=b.z; vxr[3]=b.w;
                vzr[0]=c.x; vzr[1]=c.y; vzr[2]=c.z; vzr[3]=c.w;
            }
            // No barrier here: loop-top refresh + barrier orders LDS use,
            // and ring rows are disjoint from receiver (central) rows.
        } else {
            if (rown) obase[(size_t)(l * TS + TS - 1) * NRc] = sp[rj];
        }
    }
}

extern "C" void kernel_launch(void* const* d_in, const int* in_sizes, int n_in,
                              void* d_out, int out_size, void* d_ws, size_t ws_size,
                              hipStream_t stream)
{
    const float* vp      = (const float*)d_in[0];
    const float* rho     = (const float*)d_in[1];
    const float* damp    = (const float*)d_in[2];
    const float* wavelet = (const float*)d_in[3];
    const int*   src_x   = (const int*)d_in[4];
    const int*   src_z   = (const int*)d_in[5];
    const int*   rcv_x   = (const int*)d_in[6];
    const int*   rcv_z   = (const int*)d_in[7];
    float* out = (float*)d_out;
    float* ws  = (float*)d_ws;

    const size_t F = (size_t)NSc * NXZ;
    float* xchg = ws;                              // 6 fields (2 parities)
    unsigned* flags = (unsigned*)(ws + 6 * F);     // 256 epoch counters

    // Flags must start at 0 every call (ws poisoned once, not re-poisoned).
    hipMemsetAsync(flags, 0, NBLK * sizeof(unsigned), stream);

    prop_kernel<<<NBLK, BT, 0, stream>>>(
        xchg, flags, vp, rho, damp, wavelet,
        src_x, src_z, rcv_x, rcv_z, out);
}

// Round 12
// 351.872 us; speedup vs baseline: 1.0460x; 1.0460x over previous
//
#include <hip/hip_runtime.h>

// Acoustic stress-velocity FD propagator, MI355X — persistent kernel v12.
// v6's PROVEN all-far (sc0 sc1 MALL-coherent) protocol — 3 hangs taught us
// near-scope (per-XCD L2) sync is undebuggable; never again. Changes vs v6,
// all contention-free:
//  1) proxy polling (9 threads/block) kept, with s_sleep(2) (v11's 276
//     self-pollers/block added ~70K spinning MALL loads -> +40us);
//  2) central-tile publish issued inside tau=7's pressure phase (store
//     latency hides under sp-write + barrier + drain);
//  3) tau-7 receiver record after the flag store (overlaps polls);
//  4) ring reload writes straight into LDS; central sp/spE already correct
//     from tau-7 -> the full-block loop-top refresh + one barrier deleted.
// Parity double-buffer + flag transitivity close the WAR race as in v5/v6.

#define NXc 256
#define NZc 256
#define NTc 400
#define NSc 4
#define NRc 128

#define TS 8                    // steps per epoch = halo depth
#define Bt 32                   // tile edge
#define NSTR 12                 // 4-wide strips per region row
#define BT 576                  // threads = 48 rows x 12 strips
#define LROW 48                 // region edge / LDS row stride
#define LSZ ((48 + 2) * LROW)   // 2400: one pad row above/below
#define NBLK (NSc * 64)         // 256 blocks
#define NEP (NTc / TS)          // 50 epochs

constexpr float DT_H    = 0.001f;
constexpr float INV_D   = 0.1f;            // 1/DX = 1/DZ
constexpr float SRC_AMP = 0.001f * 0.01f;  // DT/(DX*DZ)
constexpr int   NXZ     = NXc * NZc;

typedef float f32x4 __attribute__((ext_vector_type(4)));

__device__ __forceinline__ unsigned ldu_far(const unsigned* p) {
    unsigned v;
    asm volatile("global_load_dword %0, %1, off sc0 sc1\n\t"
                 "s_waitcnt vmcnt(0)" : "=&v"(v) : "v"(p) : "memory");
    return v;
}
__device__ __forceinline__ void stu_far(unsigned* p, unsigned v) {
    asm volatile("global_store_dword %0, %1, off sc0 sc1"
                 :: "v"(p), "v"(v) : "memory");
}

__global__ __launch_bounds__(BT) void prop_kernel(
    float* __restrict__ xchg, unsigned* __restrict__ flags,
    const float* __restrict__ vp, const float* __restrict__ rho,
    const float* __restrict__ damp, const float* __restrict__ wavelet,
    const int* __restrict__ src_x, const int* __restrict__ src_z,
    const int* __restrict__ rcv_x, const int* __restrict__ rcv_z,
    float* __restrict__ out)
{
    __shared__ float sp[LSZ], svx[LSZ];
    __shared__ float spE[BT + 1], svzE[BT + 1];

    const int tid  = threadIdx.x;
    const int bid  = blockIdx.x;
    const int s    = bid >> 6;
    const int tile = bid & 63;
    const int tx = tile >> 3, tz = tile & 7;
    const int gx0 = tx * Bt - TS, gz0 = tz * Bt - TS;

    const int li  = tid / NSTR;            // region row 0..47
    const int st  = tid - li * NSTR;       // strip 0..11
    const int lk0 = st * 4;
    const int gi  = gx0 + li;
    const int gk0 = gz0 + lk0;             // 4-aligned; strip fully in or out
    const bool in = ((unsigned)gi < (unsigned)NXc) &&
                    ((unsigned)gk0 < (unsigned)NZc);
    const int c4 = s * NXZ + gi * NZc + gk0;
    const bool central = in && ((unsigned)(li - TS) < (unsigned)Bt)
                            && (lk0 >= TS) && (lk0 <= TS + Bt - 4);
    const bool ring = in && !central;

    const size_t F = (size_t)NSc * NXZ;
    float* b0 = xchg;            // epoch parity 0: {p, vx, vz}
    float* b1 = xchg + 3 * F;    // epoch parity 1

    // ---- time-invariant per-cell coefficients (registers, once) ----
    float pr[4]  = {0, 0, 0, 0};
    float vxr[4] = {0, 0, 0, 0};
    float vzr[4] = {0, 0, 0, 0};
    float fr[4], bxr[4], bzr[4], dkxr[4], dkzr[4], sfr[4];
    {
        const int sx = src_x[s], sz = src_z[s];
        if (in) {
            float4 r4 = *(const float4*)(rho  + c4 - s * NXZ);
            float4 v4 = *(const float4*)(vp   + c4 - s * NXZ);
            float4 d4 = *(const float4*)(damp + c4 - s * NXZ);
            float rv[4] = {r4.x, r4.y, r4.z, r4.w};
            float vv[4] = {v4.x, v4.y, v4.z, v4.w};
            float dv[4] = {d4.x, d4.y, d4.z, d4.w};
#pragma unroll
            for (int k = 0; k < 4; ++k) {
                int gk = gk0 + k;
                fr[k] = 1.0f - DT_H * dv[k];
                float bi = DT_H / rv[k] * INV_D;
                bxr[k] = (gi == NXc - 1) ? 0.f : bi;   // _dxf zero-pad
                bzr[k] = (gk == NZc - 1) ? 0.f : bi;   // _dzf zero-pad
                float dk = DT_H * rv[k] * vv[k] * vv[k] * INV_D;
                dkxr[k] = (gi == 0) ? 0.f : dk;        // _dxb zero-pad
                dkzr[k] = (gk == 0) ? 0.f : dk;        // _dzb zero-pad
                sfr[k]  = (gi == sx && gk == sz) ? SRC_AMP : 0.f;
            }
        } else {
#pragma unroll
            for (int k = 0; k < 4; ++k) {
                fr[k] = 0.f; bxr[k] = 0.f; bzr[k] = 0.f;
                dkxr[k] = 0.f; dkzr[k] = 0.f; sfr[k] = 0.f;
            }
        }
    }

    // Pads (never overwritten: steps write rows 1..48 only).
    if (tid < LROW) {
        sp[tid] = 0.f; svx[tid] = 0.f;
        sp[LSZ - LROW + tid] = 0.f; svx[LSZ - LROW + tid] = 0.f;
    }
    if (tid == 0) { svzE[0] = 0.f; spE[BT] = 0.f; }

    // Receivers (loaded once).
    int rxv = 0, rzv = 0;
    if (tid < NRc) { rxv = rcv_x[tid]; rzv = rcv_z[tid]; }
    const bool rown = (tid < NRc) &&
        ((unsigned)(rxv - tx * Bt) < (unsigned)Bt) &&
        ((unsigned)(rzv - tz * Bt) < (unsigned)Bt);
    const int rj = (rxv - gx0 + 1) * LROW + (rzv - gz0);
    float* obase = out + (size_t)s * NTc * NRc + tid;
    const float* wb = wavelet + s * NTc;

    // Proxy-poll neighbor (tids 0..8, minus center 4).
    int nbid = -1;
    if (tid < 9 && tid != 4) {
        int dx = tid / 3 - 1, dz = tid - (tid / 3) * 3 - 1;
        int nx2 = tx + dx, nz2 = tz + dz;
        if (((unsigned)nx2 < 8u) && ((unsigned)nz2 < 8u))
            nbid = (s << 6) + nx2 * 8 + nz2;
    }

    const int jb = (li + 1) * LROW + lk0;

    // Initial LDS state (zeros / loaded regs).
    *(float4*)&sp[jb] = make_float4(pr[0], pr[1], pr[2], pr[3]);
    spE[tid] = pr[0];

    for (int l = 0; l < NEP; ++l) {
        const bool notLast = (l < NEP - 1);
        float* pb = (l & 1) ? b1 : b0;
        __syncthreads();   // orders init / ring-reload LDS writes

        for (int tau = 0; tau < TS; ++tau) {
            // ---- velocity: reads sp/spE, writes svx + vz edge line ----
            float4 pn4 = *(const float4*)&sp[jb + LROW];  // row+1 strip
            float  pze = spE[tid + 1];                    // next strip p[0]
            float pnx[4] = {pn4.x, pn4.y, pn4.z, pn4.w};
            float pz1[4] = {pr[1], pr[2], pr[3], pze};
#pragma unroll
            for (int k = 0; k < 4; ++k) {
                vxr[k] = fr[k] * vxr[k] - bxr[k] * (pnx[k] - pr[k]);
                vzr[k] = fr[k] * vzr[k] - bzr[k] * (pz1[k] - pr[k]);
            }
            *(float4*)&svx[jb] = make_float4(vxr[0], vxr[1], vxr[2], vxr[3]);
            svzE[tid + 1] = vzr[3];
            __syncthreads();

            // ---- pressure: reads svx + edge line, writes sp/spE ----
            const float wv = wb[l * TS + tau];
            float4 vxm4 = *(const float4*)&svx[jb - LROW]; // row-1 (new vx)
            float  vzm0 = svzE[tid];                       // prev strip vz[3]
            float vxm[4] = {vxm4.x, vxm4.y, vxm4.z, vxm4.w};
            float vzm[4] = {vzm0, vzr[0], vzr[1], vzr[2]};
#pragma unroll
            for (int k = 0; k < 4; ++k) {
                pr[k] = fr[k] * pr[k]
                      - dkxr[k] * (vxr[k] - vxm[k])
                      - dkzr[k] * (vzr[k] - vzm[k])
                      + sfr[k] * wv;
            }
            // Publish overlapped: issue MALL stores as soon as final pr is
            // known; latency hides under sp-write + barrier + drain.
            if (tau == TS - 1 && notLast && central) {
                f32x4 a = {pr[0], pr[1], pr[2], pr[3]};
                f32x4 b = {vxr[0], vxr[1], vxr[2], vxr[3]};
                f32x4 c = {vzr[0], vzr[1], vzr[2], vzr[3]};
                asm volatile(
                    "global_store_dwordx4 %0, %3, off sc0 sc1\n\t"
                    "global_store_dwordx4 %1, %4, off sc0 sc1\n\t"
                    "global_store_dwordx4 %2, %5, off sc0 sc1"
                    :: "v"(pb + c4), "v"(pb + F + c4), "v"(pb + 2 * F + c4),
                       "v"(a), "v"(b), "v"(c)
                    : "memory");
            }
            *(float4*)&sp[jb] = make_float4(pr[0], pr[1], pr[2], pr[3]);
            spE[tid] = pr[0];
            __syncthreads();

            // Receiver record taus 0..6 (tau 7 below, overlapped with
            // polls). sp stable through next velocity phase.
            if (tau < TS - 1 && rown)
                obase[(size_t)(l * TS + tau) * NRc] = sp[rj];
        }

        if (notLast) {
            // Release: drain publish (+receiver) stores, then flag.
            asm volatile("s_waitcnt vmcnt(0)" ::: "memory");
            __syncthreads();
            if (tid == 0) stu_far(flags + bid, (unsigned)(l + 1));
            // tau-7 receiver record overlaps the polls.
            if (rown) obase[(size_t)(l * TS + TS - 1) * NRc] = sp[rj];
            // Proxy poll: 8 threads watch the 8 neighbors.
            if (nbid >= 0) {
                const unsigned want = (unsigned)(l + 1);
                const unsigned* fp = flags + nbid;
                while (ldu_far(fp) < want) __builtin_amdgcn_s_sleep(2);
            }
            __syncthreads();
            // Ring reload -> straight into regs + LDS (central strips'
            // sp/spE already hold tau-7 values; loop-top barrier orders).
            if (ring) {
                f32x4 a, b, c;
                asm volatile(
                    "global_load_dwordx4 %0, %3, off sc0 sc1\n\t"
                    "global_load_dwordx4 %1, %4, off sc0 sc1\n\t"
                    "global_load_dwordx4 %2, %5, off sc0 sc1\n\t"
                    "s_waitcnt vmcnt(0)"
                    : "=&v"(a), "=&v"(b), "=&v"(c)
                    : "v"(pb + c4), "v"(pb + F + c4), "v"(pb + 2 * F + c4)
                    : "memory");
                pr[0]=a.x; pr[1]=a.y; pr[2]=a.z; pr[3]=a.w;
                vxr[0]=b.x; vxr[1]=b.y; vxr[2]=b.z; vxr[3]=b.w;
                vzr[0]=c.x; vzr[1]=c.y; vzr[2]=c.z; vzr[3]=c.w;
                *(float4*)&sp[jb] = make_float4(pr[0], pr[1], pr[2], pr[3]);
                spE[tid] = pr[0];
            }
        } else {
            if (rown) obase[(size_t)(l * TS + TS - 1) * NRc] = sp[rj];
        }
    }
}

extern "C" void kernel_launch(void* const* d_in, const int* in_sizes, int n_in,
                              void* d_out, int out_size, void* d_ws, size_t ws_size,
                              hipStream_t stream)
{
    const float* vp      = (const float*)d_in[0];
    const float* rho     = (const float*)d_in[1];
    const float* damp    = (const float*)d_in[2];
    const float* wavelet = (const float*)d_in[3];
    const int*   src_x   = (const int*)d_in[4];
    const int*   src_z   = (const int*)d_in[5];
    const int*   rcv_x   = (const int*)d_in[6];
    const int*   rcv_z   = (const int*)d_in[7];
    float* out = (float*)d_out;
    float* ws  = (float*)d_ws;

    const size_t F = (size_t)NSc * NXZ;
    float* xchg = ws;                              // 6 fields (2 parities)
    unsigned* flags = (unsigned*)(ws + 6 * F);     // 256 epoch counters

    // Flags must start at 0 every call (ws poisoned once, not re-poisoned).
    hipMemsetAsync(flags, 0, NBLK * sizeof(unsigned), stream);

    prop_kernel<<<NBLK, BT, 0, stream>>>(
        xchg, flags, vp, rho, damp, wavelet,
        src_x, src_z, rcv_x, rcv_z, out);
}

// Round 13
// 327.012 us; speedup vs baseline: 1.1255x; 1.0760x over previous
//
#include <hip/hip_runtime.h>

// Acoustic stress-velocity FD propagator, MI355X — persistent kernel v13.
// v6/v12's PROVEN all-far (sc0 sc1 MALL-coherent) protocol, TS doubled to
// 16 to amortize the ~4.6us/epoch sync latency over 2x the steps:
//   NEP 50 -> 25, region 64x64 (Bt=32 + 2*16), BT=1024 (64 rows x 16
//   strips), 1 block/CU. Sync chain untouched (proven deadlock-free).
// LROW=64 -> 16 strips/row = 4 rows/wave exactly, so z-edge exchange uses
// __shfl_up/down instead of LDS edge arrays (wrong-lane values land only on
// region-edge cells = trapezoid garbage ring; domain-boundary cells are
// protected by the dkz/bz coefficient masks). Parity double-buffer + flag
// transitivity close the WAR race as in v5-v12.

#define NXc 256
#define NZc 256
#define NTc 400
#define NSc 4
#define NRc 128

#define TS 16                   // steps per epoch = halo depth
#define Bt 32                   // tile edge
#define LROW 64                 // region edge (z) = Bt + 2*TS
#define ROWS 64                 // region edge (x)
#define NSTR 16                 // 4-wide strips per region row
#define BT 1024                 // threads = 64 rows x 16 strips
#define LSZ ((ROWS + 2) * LROW) // 4224: one pad row above/below
#define NBLK (NSc * 64)         // 256 blocks
#define NEP (NTc / TS)          // 25 epochs

constexpr float DT_H    = 0.001f;
constexpr float INV_D   = 0.1f;            // 1/DX = 1/DZ
constexpr float SRC_AMP = 0.001f * 0.01f;  // DT/(DX*DZ)
constexpr int   NXZ     = NXc * NZc;

typedef float f32x4 __attribute__((ext_vector_type(4)));

__device__ __forceinline__ unsigned ldu_far(const unsigned* p) {
    unsigned v;
    asm volatile("global_load_dword %0, %1, off sc0 sc1\n\t"
                 "s_waitcnt vmcnt(0)" : "=&v"(v) : "v"(p) : "memory");
    return v;
}
__device__ __forceinline__ void stu_far(unsigned* p, unsigned v) {
    asm volatile("global_store_dword %0, %1, off sc0 sc1"
                 :: "v"(p), "v"(v) : "memory");
}

__global__ __launch_bounds__(BT) void prop_kernel(
    float* __restrict__ xchg, unsigned* __restrict__ flags,
    const float* __restrict__ vp, const float* __restrict__ rho,
    const float* __restrict__ damp, const float* __restrict__ wavelet,
    const int* __restrict__ src_x, const int* __restrict__ src_z,
    const int* __restrict__ rcv_x, const int* __restrict__ rcv_z,
    float* __restrict__ out)
{
    __shared__ float sp[LSZ], svx[LSZ];

    const int tid  = threadIdx.x;
    const int bid  = blockIdx.x;
    const int s    = bid >> 6;
    const int tile = bid & 63;
    const int tx = tile >> 3, tz = tile & 7;
    const int gx0 = tx * Bt - TS, gz0 = tz * Bt - TS;

    const int li  = tid >> 4;              // region row 0..63
    const int st  = tid & 15;              // strip 0..15
    const int lk0 = st * 4;
    const int gi  = gx0 + li;
    const int gk0 = gz0 + lk0;             // 4-aligned; strip fully in or out
    const bool in = ((unsigned)gi < (unsigned)NXc) &&
                    ((unsigned)gk0 < (unsigned)NZc);
    const int c4 = s * NXZ + gi * NZc + gk0;
    const bool central = in && ((unsigned)(li - TS) < (unsigned)Bt)
                            && (lk0 >= TS) && (lk0 <= TS + Bt - 4);
    const bool ring = in && !central;

    const size_t F = (size_t)NSc * NXZ;
    float* b0 = xchg;            // epoch parity 0: {p, vx, vz}
    float* b1 = xchg + 3 * F;    // epoch parity 1

    // ---- time-invariant per-cell coefficients (registers, once) ----
    float pr[4]  = {0, 0, 0, 0};
    float vxr[4] = {0, 0, 0, 0};
    float vzr[4] = {0, 0, 0, 0};
    float fr[4], bxr[4], bzr[4], dkxr[4], dkzr[4], sfr[4];
    {
        const int sx = src_x[s], sz = src_z[s];
        if (in) {
            float4 r4 = *(const float4*)(rho  + c4 - s * NXZ);
            float4 v4 = *(const float4*)(vp   + c4 - s * NXZ);
            float4 d4 = *(const float4*)(damp + c4 - s * NXZ);
            float rv[4] = {r4.x, r4.y, r4.z, r4.w};
            float vv[4] = {v4.x, v4.y, v4.z, v4.w};
            float dv[4] = {d4.x, d4.y, d4.z, d4.w};
#pragma unroll
            for (int k = 0; k < 4; ++k) {
                int gk = gk0 + k;
                fr[k] = 1.0f - DT_H * dv[k];
                float bi = DT_H / rv[k] * INV_D;
                bxr[k] = (gi == NXc - 1) ? 0.f : bi;   // _dxf zero-pad
                bzr[k] = (gk == NZc - 1) ? 0.f : bi;   // _dzf zero-pad
                float dk = DT_H * rv[k] * vv[k] * vv[k] * INV_D;
                dkxr[k] = (gi == 0) ? 0.f : dk;        // _dxb zero-pad
                dkzr[k] = (gk == 0) ? 0.f : dk;        // _dzb zero-pad
                sfr[k]  = (gi == sx && gk == sz) ? SRC_AMP : 0.f;
            }
        } else {
#pragma unroll
            for (int k = 0; k < 4; ++k) {
                fr[k] = 0.f; bxr[k] = 0.f; bzr[k] = 0.f;
                dkxr[k] = 0.f; dkzr[k] = 0.f; sfr[k] = 0.f;
            }
        }
    }

    // Pads (never overwritten: steps write rows 1..ROWS only).
    if (tid < LROW) {
        sp[tid] = 0.f; svx[tid] = 0.f;
        sp[LSZ - LROW + tid] = 0.f; svx[LSZ - LROW + tid] = 0.f;
    }

    // Receivers (loaded once).
    int rxv = 0, rzv = 0;
    if (tid < NRc) { rxv = rcv_x[tid]; rzv = rcv_z[tid]; }
    const bool rown = (tid < NRc) &&
        ((unsigned)(rxv - tx * Bt) < (unsigned)Bt) &&
        ((unsigned)(rzv - tz * Bt) < (unsigned)Bt);
    const int rj = (rxv - gx0 + 1) * LROW + (rzv - gz0);
    float* obase = out + (size_t)s * NTc * NRc + tid;
    const float* wb = wavelet + s * NTc;

    // Proxy-poll neighbor (tids 0..8, minus center 4).
    int nbid = -1;
    if (tid < 9 && tid != 4) {
        int dx = tid / 3 - 1, dz = tid - (tid / 3) * 3 - 1;
        int nx2 = tx + dx, nz2 = tz + dz;
        if (((unsigned)nx2 < 8u) && ((unsigned)nz2 < 8u))
            nbid = (s << 6) + nx2 * 8 + nz2;
    }

    const int jb = (li + 1) * LROW + lk0;

    // Initial LDS state (zeros / loaded regs).
    *(float4*)&sp[jb] = make_float4(pr[0], pr[1], pr[2], pr[3]);

    for (int l = 0; l < NEP; ++l) {
        const bool notLast = (l < NEP - 1);
        float* pb = (l & 1) ? b1 : b0;
        __syncthreads();   // orders init / ring-reload LDS writes

        for (int tau = 0; tau < TS; ++tau) {
            // ---- velocity: reads sp + shfl, writes svx ----
            float4 pn4 = *(const float4*)&sp[jb + LROW];  // row+1 strip
            float  pze = __shfl_down(pr[0], 1, 64);       // next strip p[0]
            // (st==15 lanes get wrong data -> affects only region-edge cell
            //  63 of the row = trapezoid garbage ring)
            float pnx[4] = {pn4.x, pn4.y, pn4.z, pn4.w};
            float pz1[4] = {pr[1], pr[2], pr[3], pze};
#pragma unroll
            for (int k = 0; k < 4; ++k) {
                vxr[k] = fr[k] * vxr[k] - bxr[k] * (pnx[k] - pr[k]);
                vzr[k] = fr[k] * vzr[k] - bzr[k] * (pz1[k] - pr[k]);
            }
            *(float4*)&svx[jb] = make_float4(vxr[0], vxr[1], vxr[2], vxr[3]);
            __syncthreads();

            // ---- pressure: reads svx + shfl, writes sp ----
            const float wv = wb[l * TS + tau];
            float4 vxm4 = *(const float4*)&svx[jb - LROW]; // row-1 (new vx)
            float  vzm0 = __shfl_up(vzr[3], 1, 64);        // prev strip vz[3]
            // (st==0 lanes get wrong data -> affects only region-edge cell 0
            //  = garbage ring; domain z-boundary masked by dkzr[0]=0)
            float vxm[4] = {vxm4.x, vxm4.y, vxm4.z, vxm4.w};
            float vzm[4] = {vzm0, vzr[0], vzr[1], vzr[2]};
#pragma unroll
            for (int k = 0; k < 4; ++k) {
                pr[k] = fr[k] * pr[k]
                      - dkxr[k] * (vxr[k] - vxm[k])
                      - dkzr[k] * (vzr[k] - vzm[k])
                      + sfr[k] * wv;
            }
            // Publish overlapped: issue MALL stores as soon as final pr is
            // known; latency hides under sp-write + barrier + drain.
            if (tau == TS - 1 && notLast && central) {
                f32x4 a = {pr[0], pr[1], pr[2], pr[3]};
                f32x4 b = {vxr[0], vxr[1], vxr[2], vxr[3]};
                f32x4 c = {vzr[0], vzr[1], vzr[2], vzr[3]};
                asm volatile(
                    "global_store_dwordx4 %0, %3, off sc0 sc1\n\t"
                    "global_store_dwordx4 %1, %4, off sc0 sc1\n\t"
                    "global_store_dwordx4 %2, %5, off sc0 sc1"
                    :: "v"(pb + c4), "v"(pb + F + c4), "v"(pb + 2 * F + c4),
                       "v"(a), "v"(b), "v"(c)
                    : "memory");
            }
            *(float4*)&sp[jb] = make_float4(pr[0], pr[1], pr[2], pr[3]);
            __syncthreads();

            // Receiver record taus 0..TS-2 (last tau below, overlapped with
            // polls). sp stable through next velocity phase.
            if (tau < TS - 1 && rown)
                obase[(size_t)(l * TS + tau) * NRc] = sp[rj];
        }

        if (notLast) {
            // Release: drain publish (+receiver) stores, then flag.
            asm volatile("s_waitcnt vmcnt(0)" ::: "memory");
            __syncthreads();
            if (tid == 0) stu_far(flags + bid, (unsigned)(l + 1));
            // last-tau receiver record overlaps the polls.
            if (rown) obase[(size_t)(l * TS + TS - 1) * NRc] = sp[rj];
            // Proxy poll: 8 threads watch the 8 neighbors.
            if (nbid >= 0) {
                const unsigned want = (unsigned)(l + 1);
                const unsigned* fp = flags + nbid;
                while (ldu_far(fp) < want) __builtin_amdgcn_s_sleep(2);
            }
            __syncthreads();
            // Ring reload -> regs + LDS (central strips' sp already holds
            // last-tau values; loop-top barrier orders the LDS writes).
            if (ring) {
                f32x4 a, b, c;
                asm volatile(
                    "global_load_dwordx4 %0, %3, off sc0 sc1\n\t"
                    "global_load_dwordx4 %1, %4, off sc0 sc1\n\t"
                    "global_load_dwordx4 %2, %5, off sc0 sc1\n\t"
                    "s_waitcnt vmcnt(0)"
                    : "=&v"(a), "=&v"(b), "=&v"(c)
                    : "v"(pb + c4), "v"(pb + F + c4), "v"(pb + 2 * F + c4)
                    : "memory");
                pr[0]=a.x; pr[1]=a.y; pr[2]=a.z; pr[3]=a.w;
                vxr[0]=b.x; vxr[1]=b.y; vxr[2]=b.z; vxr[3]=b.w;
                vzr[0]=c.x; vzr[1]=c.y; vzr[2]=c.z; vzr[3]=c.w;
                *(float4*)&sp[jb] = make_float4(pr[0], pr[1], pr[2], pr[3]);
            }
        } else {
            if (rown) obase[(size_t)(l * TS + TS - 1) * NRc] = sp[rj];
        }
    }
}

extern "C" void kernel_launch(void* const* d_in, const int* in_sizes, int n_in,
                              void* d_out, int out_size, void* d_ws, size_t ws_size,
                              hipStream_t stream)
{
    const float* vp      = (const float*)d_in[0];
    const float* rho     = (const float*)d_in[1];
    const float* damp    = (const float*)d_in[2];
    const float* wavelet = (const float*)d_in[3];
    const int*   src_x   = (const int*)d_in[4];
    const int*   src_z   = (const int*)d_in[5];
    const int*   rcv_x   = (const int*)d_in[6];
    const int*   rcv_z   = (const int*)d_in[7];
    float* out = (float*)d_out;
    float* ws  = (float*)d_ws;

    const size_t F = (size_t)NSc * NXZ;
    float* xchg = ws;                              // 6 fields (2 parities)
    unsigned* flags = (unsigned*)(ws + 6 * F);     // 256 epoch counters

    // Flags must start at 0 every call (ws poisoned once, not re-poisoned).
    hipMemsetAsync(flags, 0, NBLK * sizeof(unsigned), stream);

    prop_kernel<<<NBLK, BT, 0, stream>>>(
        xchg, flags, vp, rho, damp, wavelet,
        src_x, src_z, rcv_x, rcv_z, out);
}